// Round 5
// baseline (354.720 us; speedup 1.0000x reference)
//
#include <hip/hip_runtime.h>
#include <math.h>

#define DIM 256
#define TM 128
#define TN 128
#define BK 64

typedef __bf16 bf16x8 __attribute__((ext_vector_type(8)));
typedef float f32x4 __attribute__((ext_vector_type(4)));

typedef const __attribute__((address_space(1))) void* gas_ptr;
typedef __attribute__((address_space(3))) void* las_ptr;

__device__ __forceinline__ void async_cp16(const void* g, void* l) {
    __builtin_amdgcn_global_load_lds((gas_ptr)g, (las_ptr)l, 16, 0, 0);
}

__device__ __forceinline__ unsigned short f32_to_bf16(float f) {
    unsigned int u = __float_as_uint(f);
    u += 0x7FFFu + ((u >> 16) & 1u);   // RNE; inputs are finite normals
    return (unsigned short)(u >> 16);
}

// ---------------------------------------------------------------------------
// Kernel 1: fp32 -> bf16 convert + exact fp32 row norms + exact fp32 diagonal
// cross-dots (c_i . s_i) + zero-init of accumulators and ticket.
// Waves with row < N additionally load S row i for the diag dot; the diag
// path is thus written by THIS kernel, so the GEMM's last-block reduction
// never depends on peer-block plain stores (only device-scope atomics).
// ---------------------------------------------------------------------------
__global__ __launch_bounds__(256) void convert_kernel(
        const float* __restrict__ C, const float* __restrict__ S,
        unsigned short* __restrict__ Cb, unsigned short* __restrict__ Sb,
        float* __restrict__ c2, float* __restrict__ s2,
        float* __restrict__ ddot,           // c_i . s_i, N floats
        float* __restrict__ sums0,          // rowsum..colsum, 2N floats
        unsigned int* __restrict__ ticket, int N) {
    int gtid = blockIdx.x * 256 + threadIdx.x;
    if (gtid < 2 * N) sums0[gtid] = 0.0f;
    if (gtid == 0) *ticket = 0u;
    int row = gtid >> 6;
    int lane = gtid & 63;
    if (row >= 2 * N) return;
    if (row < N) {
        const float* src = C + (size_t)row * DIM;
        float4 v = ((const float4*)src)[lane];
        float4 sv = ((const float4*)(S + (size_t)row * DIM))[lane];
        ushort4 b;
        b.x = f32_to_bf16(v.x); b.y = f32_to_bf16(v.y);
        b.z = f32_to_bf16(v.z); b.w = f32_to_bf16(v.w);
        ((ushort4*)(Cb + (size_t)row * DIM))[lane] = b;
        float nrm = v.x * v.x + v.y * v.y + v.z * v.z + v.w * v.w;
        float cr  = v.x * sv.x + v.y * sv.y + v.z * sv.z + v.w * sv.w;
        #pragma unroll
        for (int off = 32; off > 0; off >>= 1) {
            nrm += __shfl_down(nrm, off, 64);
            cr  += __shfl_down(cr,  off, 64);
        }
        if (lane == 0) { c2[row] = nrm; ddot[row] = cr; }
    } else {
        int r = row - N;
        const float* src = S + (size_t)r * DIM;
        float4 v = ((const float4*)src)[lane];
        ushort4 b;
        b.x = f32_to_bf16(v.x); b.y = f32_to_bf16(v.y);
        b.z = f32_to_bf16(v.z); b.w = f32_to_bf16(v.w);
        ((ushort4*)(Sb + (size_t)r * DIM))[lane] = b;
        float nrm = v.x * v.x + v.y * v.y + v.z * v.z + v.w * v.w;
        #pragma unroll
        for (int off = 32; off > 0; off >>= 1) nrm += __shfl_down(nrm, off, 64);
        if (lane == 0) s2[r] = nrm;
    }
}

// ---------------------------------------------------------------------------
// Kernel 2: bf16 MFMA GEMM (128x128 tile, BK=64, XOR-swizzled LDS; staging
// via wave-uniform global_load_lds and ds_read_b128 frag reads are both
// conflict-free). Fused epilogue: e = exp(-dist*e^T); row/col sums via
// shuffle reduce -> LDS -> 1 device-scope atomic per row/col per block.
// sim in [-50,0]: single-pass logsumexp is exact in fp32 range.
// __launch_bounds__(256,3): 92 VGPR + 64 AGPR = 156 <= 170 (512/3), so the
// cap costs nothing and lifts residency 2 -> 3 blocks/CU (R3 measured 2).
// Loss computed by the LAST block (ticket), reading only values from the
// prior kernel (c2/s2/ddot) and device-scope atomic results (rowsum/colsum).
// ---------------------------------------------------------------------------
__global__ __launch_bounds__(256, 3) void mfma_kernel(
        const unsigned short* __restrict__ Cb, const unsigned short* __restrict__ Sb,
        const float* __restrict__ c2, const float* __restrict__ s2,
        const float* __restrict__ ddot, const float* __restrict__ temp,
        float* __restrict__ rowsum, float* __restrict__ colsum,
        unsigned int* __restrict__ ticket, float* __restrict__ out, int N) {
    __shared__ __align__(16) unsigned short Abuf[TM * BK];   // 16 KB
    __shared__ __align__(16) unsigned short Bbuf[TN * BK];   // 16 KB
    __shared__ float rs[TM], cs[TN], c2t[TM], s2t[TN];
    __shared__ float fred[4];
    __shared__ unsigned int my_ticket;

    const int tid = threadIdx.x;
    const int bm = blockIdx.y * TM;
    const int bn = blockIdx.x * TN;
    const int w  = tid >> 6;
    const int l  = tid & 63;
    const int wm = (w >> 1) * 64;
    const int wn = (w & 1) * 64;

    if (tid < TM) { rs[tid] = 0.0f; c2t[tid] = c2[bm + tid]; }
    else          { int t = tid - TM; cs[t] = 0.0f; s2t[t] = s2[bn + t]; }

    // --- staging: slot s = i*256 + w*64 + l <-> (row = s>>3, pchunk = s&7)
    // data for (row, pchunk) = global chunk pchunk ^ (row&7); row&7 == l>>3.
    const int l8 = l >> 3, l7 = l & 7;
    const int gch = l7 ^ l8;
    const unsigned short* gAl = Cb + (size_t)(bm + w * 8 + l8) * DIM + gch * 8;
    const unsigned short* gBl = Sb + (size_t)(bn + w * 8 + l8) * DIM + gch * 8;
    unsigned short* lA = &Abuf[w * 512];
    unsigned short* lB = &Bbuf[w * 512];
    const size_t istep = (size_t)32 * DIM;    // +32 rows per staging instr

    // --- fragment offsets: A[m = l&15][k = q*8+j], q = l>>4.
    const int m16 = l & 15;
    const int q = l >> 4;
    const int m7 = m16 & 7;
    int aoff[4], boff[4];
    #pragma unroll
    for (int i = 0; i < 4; ++i) {
        aoff[i] = (wm + i * 16 + m16) * BK + (q ^ m7) * 8;
        boff[i] = (wn + i * 16 + m16) * BK + (q ^ m7) * 8;
    }

    f32x4 acc[4][4] = {};

    #pragma unroll
    for (int kk = 0; kk < 4; ++kk) {
        #pragma unroll
        for (int i = 0; i < 4; ++i) {
            async_cp16(gAl + i * istep, lA + i * 2048);
            async_cp16(gBl + i * istep, lB + i * 2048);
        }
        gAl += BK; gBl += BK;
        __syncthreads();   // staging complete (vmcnt drain)

        #pragma unroll
        for (int t = 0; t < 2; ++t) {
            bf16x8 af[4], bf[4];
            #pragma unroll
            for (int i = 0; i < 4; ++i) af[i] = *(const bf16x8*)&Abuf[aoff[i] ^ (t << 5)];
            #pragma unroll
            for (int i = 0; i < 4; ++i) bf[i] = *(const bf16x8*)&Bbuf[boff[i] ^ (t << 5)];
            #pragma unroll
            for (int mi = 0; mi < 4; ++mi)
                #pragma unroll
                for (int ni = 0; ni < 4; ++ni)
                    acc[mi][ni] = __builtin_amdgcn_mfma_f32_16x16x32_bf16(
                        af[mi], bf[ni], acc[mi][ni], 0, 0, 0);
        }
        __syncthreads();   // LDS consumed
    }

    // --- fused epilogue; C/D layout (m89): col = lane&15, row = q*4 + reg.
    const float escale = __expf(temp[0]);

    float c2v[4][4], s2v[4];
    #pragma unroll
    for (int mi = 0; mi < 4; ++mi)
        #pragma unroll
        for (int r = 0; r < 4; ++r) c2v[mi][r] = c2t[wm + mi * 16 + q * 4 + r];
    #pragma unroll
    for (int ni = 0; ni < 4; ++ni) s2v[ni] = s2t[wn + ni * 16 + m16];

    float rpart[4][4];
    #pragma unroll
    for (int mi = 0; mi < 4; ++mi)
        #pragma unroll
        for (int r = 0; r < 4; ++r) rpart[mi][r] = 0.0f;
    float cpart[4] = {0.f, 0.f, 0.f, 0.f};

    #pragma unroll
    for (int mi = 0; mi < 4; ++mi) {
        #pragma unroll
        for (int ni = 0; ni < 4; ++ni) {
            #pragma unroll
            for (int r = 0; r < 4; ++r) {
                float d2 = fmaf(-2.0f, acc[mi][ni][r], c2v[mi][r] + s2v[ni]);
                d2 = fmaxf(d2, 0.0f);
                float dist = __builtin_amdgcn_sqrtf(d2);
                float e = __expf(-escale * dist);
                rpart[mi][r] += e;
                cpart[ni] += e;
            }
        }
    }
    // rows: reduce across the 16 lanes sharing q
    #pragma unroll
    for (int mask = 1; mask < 16; mask <<= 1)
        #pragma unroll
        for (int mi = 0; mi < 4; ++mi)
            #pragma unroll
            for (int r = 0; r < 4; ++r)
                rpart[mi][r] += __shfl_xor(rpart[mi][r], mask, 64);
    if (m16 == 0) {
        #pragma unroll
        for (int mi = 0; mi < 4; ++mi)
            #pragma unroll
            for (int r = 0; r < 4; ++r)
                atomicAdd(&rs[wm + mi * 16 + q * 4 + r], rpart[mi][r]);
    }
    // cols: reduce across the 4 quads
    #pragma unroll
    for (int mask = 16; mask < 64; mask <<= 1)
        #pragma unroll
        for (int ni = 0; ni < 4; ++ni)
            cpart[ni] += __shfl_xor(cpart[ni], mask, 64);
    if (q == 0) {
        #pragma unroll
        for (int ni = 0; ni < 4; ++ni)
            atomicAdd(&cs[wn + ni * 16 + m16], cpart[ni]);
    }
    __syncthreads();
    if (tid < TM) atomicAdd(&rowsum[bm + tid], rs[tid]);
    else          atomicAdd(&colsum[bn + tid - TM], cs[tid - TM]);

    // --- last block computes the loss (ticket + device-scope fence) ---
    __threadfence();   // release: our rowsum/colsum atomics ordered before ticket
    if (tid == 0) my_ticket = atomicAdd(ticket, 1u);
    __syncthreads();
    const unsigned int nblocks = gridDim.x * gridDim.y;
    if (my_ticket == nblocks - 1) {
        __threadfence();   // acquire: invalidate caches; see all peers' atomics
        float sum = 0.0f;
        for (int i = tid; i < N; i += 256) {
            float d2 = c2[i] + s2[i] - 2.0f * ddot[i];
            float dist = __builtin_amdgcn_sqrtf(fmaxf(d2, 0.0f));
            sum += __logf(rowsum[i]) + __logf(colsum[i]) + 2.0f * escale * dist;
        }
        #pragma unroll
        for (int off = 32; off > 0; off >>= 1) sum += __shfl_down(sum, off, 64);
        if (l == 0) fred[w] = sum;
        __syncthreads();
        if (tid == 0)
            out[0] = (fred[0] + fred[1] + fred[2] + fred[3]) / (2.0f * (float)N);
    }
}

extern "C" void kernel_launch(void* const* d_in, const int* in_sizes, int n_in,
                              void* d_out, int out_size, void* d_ws, size_t ws_size,
                              hipStream_t stream) {
    const float* C = (const float*)d_in[0];
    const float* S = (const float*)d_in[1];
    const float* T = (const float*)d_in[2];
    const int N = in_sizes[0] / DIM;   // 8192

    float* ws     = (float*)d_ws;
    float* c2     = ws;
    float* s2     = ws + N;
    float* rowsum = ws + 2 * N;
    float* colsum = ws + 3 * N;
    float* ddot   = ws + 4 * N;
    unsigned int* ticket = (unsigned int*)(ws + 5 * N);
    unsigned short* Cb = (unsigned short*)(ws + 5 * N + 64);  // 16B-aligned
    unsigned short* Sb = Cb + (size_t)N * DIM;

    convert_kernel<<<(2 * N * 64) / 256, 256, 0, stream>>>(
        C, S, Cb, Sb, c2, s2, ddot, rowsum, ticket, N);

    dim3 grid(N / TN, N / TM);
    mfma_kernel<<<grid, 256, 0, stream>>>(
        Cb, Sb, c2, s2, ddot, T, rowsum, colsum, ticket, (float*)d_out, N);
}

// Round 6
// 145.844 us; speedup vs baseline: 2.4322x; 2.4322x over previous
//
#include <hip/hip_runtime.h>
#include <math.h>

#define DIM 256
#define TM 128
#define TN 128
#define BK 64

typedef __bf16 bf16x8 __attribute__((ext_vector_type(8)));
typedef float f32x4 __attribute__((ext_vector_type(4)));

typedef const __attribute__((address_space(1))) void* gas_ptr;
typedef __attribute__((address_space(3))) void* las_ptr;

__device__ __forceinline__ void async_cp16(const void* g, void* l) {
    __builtin_amdgcn_global_load_lds((gas_ptr)g, (las_ptr)l, 16, 0, 0);
}

__device__ __forceinline__ unsigned short f32_to_bf16(float f) {
    unsigned int u = __float_as_uint(f);
    u += 0x7FFFu + ((u >> 16) & 1u);   // RNE; inputs are finite normals
    return (unsigned short)(u >> 16);
}

// ---------------------------------------------------------------------------
// Kernel 1: fp32 -> bf16 convert + exact fp32 row norms + exact fp32 diagonal
// cross-dots (c_i . s_i) + zero-init of rowsum/colsum.
// One wave per row; lane loads one float4 (64*4 = 256 = DIM).
// ---------------------------------------------------------------------------
__global__ __launch_bounds__(256) void convert_kernel(
        const float* __restrict__ C, const float* __restrict__ S,
        unsigned short* __restrict__ Cb, unsigned short* __restrict__ Sb,
        float* __restrict__ c2, float* __restrict__ s2,
        float* __restrict__ ddot,           // c_i . s_i, N floats
        float* __restrict__ sums0, int N) { // rowsum..colsum, 2N floats
    int gtid = blockIdx.x * 256 + threadIdx.x;
    if (gtid < 2 * N) sums0[gtid] = 0.0f;
    int row = gtid >> 6;
    int lane = gtid & 63;
    if (row >= 2 * N) return;
    if (row < N) {
        float4 v  = ((const float4*)(C + (size_t)row * DIM))[lane];
        float4 sv = ((const float4*)(S + (size_t)row * DIM))[lane];
        ushort4 b;
        b.x = f32_to_bf16(v.x); b.y = f32_to_bf16(v.y);
        b.z = f32_to_bf16(v.z); b.w = f32_to_bf16(v.w);
        ((ushort4*)(Cb + (size_t)row * DIM))[lane] = b;
        float nrm = v.x * v.x + v.y * v.y + v.z * v.z + v.w * v.w;
        float cr  = v.x * sv.x + v.y * sv.y + v.z * sv.z + v.w * sv.w;
        #pragma unroll
        for (int off = 32; off > 0; off >>= 1) {
            nrm += __shfl_down(nrm, off, 64);
            cr  += __shfl_down(cr,  off, 64);
        }
        if (lane == 0) { c2[row] = nrm; ddot[row] = cr; }
    } else {
        int r = row - N;
        float4 v = ((const float4*)(S + (size_t)r * DIM))[lane];
        ushort4 b;
        b.x = f32_to_bf16(v.x); b.y = f32_to_bf16(v.y);
        b.z = f32_to_bf16(v.z); b.w = f32_to_bf16(v.w);
        ((ushort4*)(Sb + (size_t)r * DIM))[lane] = b;
        float nrm = v.x * v.x + v.y * v.y + v.z * v.z + v.w * v.w;
        #pragma unroll
        for (int off = 32; off > 0; off >>= 1) nrm += __shfl_down(nrm, off, 64);
        if (lane == 0) s2[r] = nrm;
    }
}

// ---------------------------------------------------------------------------
// Kernel 2: bf16 MFMA GEMM with fused exp/row-col-sum epilogue.
// 128x128 tile, BK=64, but 512 threads = 8 waves (2x4 grid of 64x32 wave
// tiles): half the acc registers per wave vs R3 (32 AGPR), so ~116 total
// regs -> 4 waves/SIMD -> 2 blocks/CU (~16 waves) for latency hiding.
// No device-scope fences (R5 showed per-block threadfence wrecks L2).
// XOR-swizzled LDS (pchunk = chunk ^ (row&7)): wave-uniform global_load_lds
// staging and ds_read_b128 frag reads both conflict-free.
// ---------------------------------------------------------------------------
__global__ __launch_bounds__(512, 4) void mfma_kernel(
        const unsigned short* __restrict__ Cb, const unsigned short* __restrict__ Sb,
        const float* __restrict__ c2, const float* __restrict__ s2,
        const float* __restrict__ temp,
        float* __restrict__ rowsum, float* __restrict__ colsum, int N) {
    __shared__ __align__(16) unsigned short Abuf[TM * BK];   // 16 KB
    __shared__ __align__(16) unsigned short Bbuf[TN * BK];   // 16 KB
    __shared__ float rs[TM], cs[TN], c2t[TM], s2t[TN];

    const int tid = threadIdx.x;
    const int bm = blockIdx.y * TM;
    const int bn = blockIdx.x * TN;
    const int w  = tid >> 6;        // 0..7
    const int l  = tid & 63;
    const int wm = (w >> 2) * 64;   // wave row offset: 0 or 64
    const int wn = (w & 3) * 32;    // wave col offset: 0,32,64,96

    if      (tid < 128) rs[tid] = 0.0f;
    else if (tid < 256) cs[tid - 128] = 0.0f;
    else if (tid < 384) c2t[tid - 256] = c2[bm + tid - 256];
    else                s2t[tid - 384] = s2[bn + tid - 384];

    // --- staging: slot s = i*512 + w*64 + l <-> (row = s>>3, pchunk = s&7)
    // data at (row, pchunk) = global chunk pchunk ^ (row&7); row&7 == l>>3.
    const int l8 = l >> 3;
    const int gch = (l & 7) ^ l8;
    const unsigned short* gAl = Cb + (size_t)(bm + w * 8 + l8) * DIM + gch * 8;
    const unsigned short* gBl = Sb + (size_t)(bn + w * 8 + l8) * DIM + gch * 8;
    unsigned short* lA = &Abuf[w * 512];   // + i*4096 per instr
    unsigned short* lB = &Bbuf[w * 512];
    const size_t istep = (size_t)64 * DIM;  // +64 rows for the i=1 instr

    // --- fragment offsets: A[m = l&15][k = q*8+j], q = l>>4.
    const int m16 = l & 15;
    const int q = l >> 4;
    const int m7 = m16 & 7;
    int aoff[4], boff[2];
    #pragma unroll
    for (int i = 0; i < 4; ++i)
        aoff[i] = (wm + i * 16 + m16) * BK + ((q ^ m7) * 8);
    #pragma unroll
    for (int j = 0; j < 2; ++j)
        boff[j] = (wn + j * 16 + m16) * BK + ((q ^ m7) * 8);

    f32x4 acc[4][2] = {};

    #pragma unroll
    for (int kk = 0; kk < 4; ++kk) {
        async_cp16(gAl, lA);
        async_cp16(gAl + istep, lA + 4096);
        async_cp16(gBl, lB);
        async_cp16(gBl + istep, lB + 4096);
        gAl += BK; gBl += BK;
        __syncthreads();   // staging complete (vmcnt drain)

        #pragma unroll
        for (int t = 0; t < 2; ++t) {
            bf16x8 af[4], bf[2];
            #pragma unroll
            for (int i = 0; i < 4; ++i) af[i] = *(const bf16x8*)&Abuf[aoff[i] ^ (t << 5)];
            #pragma unroll
            for (int j = 0; j < 2; ++j) bf[j] = *(const bf16x8*)&Bbuf[boff[j] ^ (t << 5)];
            #pragma unroll
            for (int mi = 0; mi < 4; ++mi)
                #pragma unroll
                for (int ni = 0; ni < 2; ++ni)
                    acc[mi][ni] = __builtin_amdgcn_mfma_f32_16x16x32_bf16(
                        af[mi], bf[ni], acc[mi][ni], 0, 0, 0);
        }
        __syncthreads();   // LDS consumed
    }

    // --- fused epilogue; C/D layout (m89): col = lane&15, row = q*4 + reg.
    const float escale = __expf(temp[0]);

    float c2v[4][4], s2v[2];
    #pragma unroll
    for (int mi = 0; mi < 4; ++mi)
        #pragma unroll
        for (int r = 0; r < 4; ++r) c2v[mi][r] = c2t[wm + mi * 16 + q * 4 + r];
    #pragma unroll
    for (int ni = 0; ni < 2; ++ni) s2v[ni] = s2t[wn + ni * 16 + m16];

    float rpart[4][4];
    #pragma unroll
    for (int mi = 0; mi < 4; ++mi)
        #pragma unroll
        for (int r = 0; r < 4; ++r) rpart[mi][r] = 0.0f;
    float cpart[2] = {0.f, 0.f};

    #pragma unroll
    for (int mi = 0; mi < 4; ++mi) {
        #pragma unroll
        for (int ni = 0; ni < 2; ++ni) {
            #pragma unroll
            for (int r = 0; r < 4; ++r) {
                float d2 = fmaf(-2.0f, acc[mi][ni][r], c2v[mi][r] + s2v[ni]);
                d2 = fmaxf(d2, 0.0f);
                float dist = __builtin_amdgcn_sqrtf(d2);
                float e = __expf(-escale * dist);
                rpart[mi][r] += e;
                cpart[ni] += e;
            }
        }
    }
    // rows: reduce across the 16 lanes sharing q
    #pragma unroll
    for (int mask = 1; mask < 16; mask <<= 1)
        #pragma unroll
        for (int mi = 0; mi < 4; ++mi)
            #pragma unroll
            for (int r = 0; r < 4; ++r)
                rpart[mi][r] += __shfl_xor(rpart[mi][r], mask, 64);
    if (m16 == 0) {
        #pragma unroll
        for (int mi = 0; mi < 4; ++mi)
            #pragma unroll
            for (int r = 0; r < 4; ++r)
                atomicAdd(&rs[wm + mi * 16 + q * 4 + r], rpart[mi][r]);
    }
    // cols: reduce across the 4 quads
    #pragma unroll
    for (int mask = 16; mask < 64; mask <<= 1)
        #pragma unroll
        for (int ni = 0; ni < 2; ++ni)
            cpart[ni] += __shfl_xor(cpart[ni], mask, 64);
    if (q == 0) {
        #pragma unroll
        for (int ni = 0; ni < 2; ++ni)
            atomicAdd(&cs[wn + ni * 16 + m16], cpart[ni]);
    }
    __syncthreads();
    if      (tid < 128) atomicAdd(&rowsum[bm + tid], rs[tid]);
    else if (tid < 256) atomicAdd(&colsum[bn + tid - 128], cs[tid - 128]);
}

// ---------------------------------------------------------------------------
// Kernel 3: finalize, single block of 1024 threads, direct write (no atomic).
// diag dist reconstructed exactly from c2/s2/ddot (fp32, from kernel 1).
// loss = (1/2N) * sum_i [log(rowsum_i) + log(colsum_i) + 2*e^T*dist_i]
// ---------------------------------------------------------------------------
__global__ __launch_bounds__(1024) void finalize_kernel(
        const float* __restrict__ rowsum, const float* __restrict__ colsum,
        const float* __restrict__ c2, const float* __restrict__ s2,
        const float* __restrict__ ddot, const float* __restrict__ temp,
        float* __restrict__ out, int N) {
    __shared__ float red[16];
    const float escale = __expf(temp[0]);
    const int tid = threadIdx.x;
    float sum = 0.0f;
    for (int i = tid; i < N; i += 1024) {
        float d2 = c2[i] + s2[i] - 2.0f * ddot[i];
        float dist = __builtin_amdgcn_sqrtf(fmaxf(d2, 0.0f));
        sum += __logf(rowsum[i]) + __logf(colsum[i]) + 2.0f * escale * dist;
    }
    #pragma unroll
    for (int off = 32; off > 0; off >>= 1) sum += __shfl_down(sum, off, 64);
    if ((tid & 63) == 0) red[tid >> 6] = sum;
    __syncthreads();
    if (tid == 0) {
        float t = 0.0f;
        #pragma unroll
        for (int i = 0; i < 16; ++i) t += red[i];
        out[0] = t / (2.0f * (float)N);
    }
}

extern "C" void kernel_launch(void* const* d_in, const int* in_sizes, int n_in,
                              void* d_out, int out_size, void* d_ws, size_t ws_size,
                              hipStream_t stream) {
    const float* C = (const float*)d_in[0];
    const float* S = (const float*)d_in[1];
    const float* T = (const float*)d_in[2];
    const int N = in_sizes[0] / DIM;   // 8192

    float* ws     = (float*)d_ws;
    float* c2     = ws;
    float* s2     = ws + N;
    float* rowsum = ws + 2 * N;
    float* colsum = ws + 3 * N;
    float* ddot   = ws + 4 * N;
    unsigned short* Cb = (unsigned short*)(ws + 5 * N + 64);  // 16B-aligned
    unsigned short* Sb = Cb + (size_t)N * DIM;

    convert_kernel<<<(2 * N * 64) / 256, 256, 0, stream>>>(
        C, S, Cb, Sb, c2, s2, ddot, rowsum, N);

    dim3 grid(N / TN, N / TM);
    mfma_kernel<<<grid, 512, 0, stream>>>(
        Cb, Sb, c2, s2, T, rowsum, colsum, N);

    finalize_kernel<<<1, 1024, 0, stream>>>(
        rowsum, colsum, c2, s2, ddot, T, (float*)d_out, N);
}

// Round 7
// 122.445 us; speedup vs baseline: 2.8970x; 1.1911x over previous
//
#include <hip/hip_runtime.h>
#include <math.h>

#define DIM 256
#define TM 256          // block tile rows (cond)
#define TN 128          // block tile cols (sol)
#define BK 64

typedef __bf16 bf16x8 __attribute__((ext_vector_type(8)));
typedef float f32x4 __attribute__((ext_vector_type(4)));

typedef const __attribute__((address_space(1))) void* gas_ptr;
typedef __attribute__((address_space(3))) void* las_ptr;

__device__ __forceinline__ void async_cp16(const void* g, void* l) {
    __builtin_amdgcn_global_load_lds((gas_ptr)g, (las_ptr)l, 16, 0, 0);
}

__device__ __forceinline__ unsigned short f32_to_bf16(float f) {
    unsigned int u = __float_as_uint(f);
    u += 0x7FFFu + ((u >> 16) & 1u);   // RNE; inputs are finite normals
    return (unsigned short)(u >> 16);
}

// ---------------------------------------------------------------------------
// Kernel 1: one wave per row index i: converts BOTH C_i and S_i to bf16,
// computes c2_i, s2_i, ddot_i = c_i.s_i (all exact fp32), zero-inits
// rowsum/colsum and out[0]. Each input row read exactly once.
// ---------------------------------------------------------------------------
__global__ __launch_bounds__(256) void convert_kernel(
        const float* __restrict__ C, const float* __restrict__ S,
        unsigned short* __restrict__ Cb, unsigned short* __restrict__ Sb,
        float* __restrict__ c2, float* __restrict__ s2,
        float* __restrict__ ddot, float* __restrict__ sums0,
        float* __restrict__ out, int N) {
    int gtid = blockIdx.x * 256 + threadIdx.x;
    if (gtid < 2 * N) sums0[gtid] = 0.0f;
    if (gtid == 0) out[0] = 0.0f;
    int row = gtid >> 6;
    int lane = gtid & 63;
    if (row >= N) return;
    float4 v  = ((const float4*)(C + (size_t)row * DIM))[lane];
    float4 sv = ((const float4*)(S + (size_t)row * DIM))[lane];
    ushort4 bc, bs;
    bc.x = f32_to_bf16(v.x);  bc.y = f32_to_bf16(v.y);
    bc.z = f32_to_bf16(v.z);  bc.w = f32_to_bf16(v.w);
    bs.x = f32_to_bf16(sv.x); bs.y = f32_to_bf16(sv.y);
    bs.z = f32_to_bf16(sv.z); bs.w = f32_to_bf16(sv.w);
    ((ushort4*)(Cb + (size_t)row * DIM))[lane] = bc;
    ((ushort4*)(Sb + (size_t)row * DIM))[lane] = bs;
    float nc = v.x * v.x + v.y * v.y + v.z * v.z + v.w * v.w;
    float ns = sv.x * sv.x + sv.y * sv.y + sv.z * sv.z + sv.w * sv.w;
    float cr = v.x * sv.x + v.y * sv.y + v.z * sv.z + v.w * sv.w;
    #pragma unroll
    for (int off = 32; off > 0; off >>= 1) {
        nc += __shfl_down(nc, off, 64);
        ns += __shfl_down(ns, off, 64);
        cr += __shfl_down(cr, off, 64);
    }
    if (lane == 0) { c2[row] = nc; s2[row] = ns; ddot[row] = cr; }
}

// ---------------------------------------------------------------------------
// Kernel 2: bf16 MFMA GEMM, 256x128 block tile, 8 waves of 64x64 wave tiles
// (4x2 wave grid). BK=64, XOR-swizzled LDS (pchunk = chunk ^ (row&7)):
// wave-uniform global_load_lds staging + conflict-free ds_read_b128 frags.
// R6 lesson: the LDS pipe is the limiter -> 64x64 wave tiles cut frag
// traffic/output by 1/3, and the epilogue uses a split-exchange fold
// (15 swizzles for 16 row-partials vs 64 in R6). No device-scope fences.
// ---------------------------------------------------------------------------
__global__ __launch_bounds__(512, 4) void mfma_kernel(
        const unsigned short* __restrict__ Cb, const unsigned short* __restrict__ Sb,
        const float* __restrict__ c2, const float* __restrict__ s2,
        const float* __restrict__ temp,
        float* __restrict__ rowsum, float* __restrict__ colsum, int N) {
    __shared__ __align__(16) unsigned short Abuf[TM * BK];   // 32 KB
    __shared__ __align__(16) unsigned short Bbuf[TN * BK];   // 16 KB
    __shared__ float rs[TM], cs[TN], c2t[TM], s2t[TN];       // 3 KB

    const int tid = threadIdx.x;
    const int bm = blockIdx.y * TM;
    const int bn = blockIdx.x * TN;
    const int w  = tid >> 6;        // 0..7
    const int l  = tid & 63;
    const int wm = (w >> 1) * 64;   // 0,64,128,192
    const int wn = (w & 1) * 64;    // 0,64

    if (tid < TM) { rs[tid] = 0.0f; c2t[tid] = c2[bm + tid]; }
    else if (tid < TM + TN) {
        int t = tid - TM; cs[t] = 0.0f; s2t[t] = s2[bn + t];
    }

    // --- staging: slot s = i*512 + w*64 + l <-> (row = s>>3, pchunk = s&7)
    // data at (row, pchunk) = global chunk pchunk ^ (row&7); row&7 == l>>3.
    const int l8 = l >> 3;
    const int gch = (l & 7) ^ l8;
    const unsigned short* gAl = Cb + (size_t)(bm + w * 8 + l8) * DIM + gch * 8;
    const unsigned short* gBl = Sb + (size_t)(bn + w * 8 + l8) * DIM + gch * 8;
    unsigned short* lA = &Abuf[w * 512];   // + i*4096 per instr
    unsigned short* lB = &Bbuf[w * 512];
    const size_t istep = (size_t)64 * DIM;  // +64 rows per instr index

    // --- fragment offsets: A[m = l&15][k = q*8+j], q = l>>4.
    const int m16 = l & 15;
    const int q = l >> 4;
    const int m7 = m16 & 7;
    int aoff[4], boff[4];
    #pragma unroll
    for (int i = 0; i < 4; ++i) {
        aoff[i] = (wm + i * 16 + m16) * BK + ((q ^ m7) * 8);
        boff[i] = (wn + i * 16 + m16) * BK + ((q ^ m7) * 8);
    }

    f32x4 acc[4][4] = {};

    #pragma unroll
    for (int kk = 0; kk < 4; ++kk) {
        #pragma unroll
        for (int i = 0; i < 4; ++i) async_cp16(gAl + i * istep, lA + i * 4096);
        #pragma unroll
        for (int i = 0; i < 2; ++i) async_cp16(gBl + i * istep, lB + i * 4096);
        gAl += BK; gBl += BK;
        __syncthreads();   // staging complete (vmcnt drain)

        #pragma unroll
        for (int t = 0; t < 2; ++t) {
            bf16x8 af[4], bf[4];
            #pragma unroll
            for (int i = 0; i < 4; ++i) af[i] = *(const bf16x8*)&Abuf[aoff[i] ^ (t << 5)];
            #pragma unroll
            for (int j = 0; j < 4; ++j) bf[j] = *(const bf16x8*)&Bbuf[boff[j] ^ (t << 5)];
            #pragma unroll
            for (int mi = 0; mi < 4; ++mi)
                #pragma unroll
                for (int ni = 0; ni < 4; ++ni)
                    acc[mi][ni] = __builtin_amdgcn_mfma_f32_16x16x32_bf16(
                        af[mi], bf[ni], acc[mi][ni], 0, 0, 0);
        }
        __syncthreads();   // LDS consumed
    }

    // --- fused epilogue; C/D layout (m89): col = lane&15, row = q*4 + reg.
    const float escale = __expf(temp[0]);

    float c2v[4][4], s2v[4];
    #pragma unroll
    for (int mi = 0; mi < 4; ++mi)
        #pragma unroll
        for (int r = 0; r < 4; ++r) c2v[mi][r] = c2t[wm + mi * 16 + q * 4 + r];
    #pragma unroll
    for (int ni = 0; ni < 4; ++ni) s2v[ni] = s2t[wn + ni * 16 + m16];

    float rp[16];   // slot s = mi*4 + r
    #pragma unroll
    for (int s = 0; s < 16; ++s) rp[s] = 0.0f;
    float cp[4] = {0.f, 0.f, 0.f, 0.f};

    #pragma unroll
    for (int mi = 0; mi < 4; ++mi) {
        #pragma unroll
        for (int ni = 0; ni < 4; ++ni) {
            #pragma unroll
            for (int r = 0; r < 4; ++r) {
                float d2 = fmaf(-2.0f, acc[mi][ni][r], c2v[mi][r] + s2v[ni]);
                d2 = fmaxf(d2, 0.0f);
                float dist = __builtin_amdgcn_sqrtf(d2);
                float e = __expf(-escale * dist);
                rp[mi * 4 + r] += e;
                cp[ni] += e;
            }
        }
    }

    // --- split-exchange fold over the 16 lanes sharing q (slot bit b must
    // match m16 bit b): after 4 stages lane holds the full sum for s = m16.
    #pragma unroll
    for (int b = 0; b < 4; ++b) {
        const int n = 16 >> b;
        const int bit = (m16 >> b) & 1;
        #pragma unroll
        for (int k = 0; k < 8; ++k) {
            if (k < (n >> 1)) {
                float keep = bit ? rp[2 * k + 1] : rp[2 * k];
                float send = bit ? rp[2 * k] : rp[2 * k + 1];
                float recv = __shfl_xor(send, 1 << b, 64);
                rp[k] = keep + recv;
            }
        }
    }
    // lane (q, m16) now holds the row-partial for:
    const int myrow = wm + (m16 >> 2) * 16 + q * 4 + (m16 & 3);
    atomicAdd(&rs[myrow], rp[0]);   // 2-way collision (wn pair) only

    // --- same fold for cp over the 4 quads (slot bit b vs q bit b)
    #pragma unroll
    for (int b = 0; b < 2; ++b) {
        const int n = 4 >> b;
        const int bit = (q >> b) & 1;
        #pragma unroll
        for (int k = 0; k < 2; ++k) {
            if (k < (n >> 1)) {
                float keep = bit ? cp[2 * k + 1] : cp[2 * k];
                float send = bit ? cp[2 * k] : cp[2 * k + 1];
                float recv = __shfl_xor(send, 16 << b, 64);
                cp[k] = keep + recv;
            }
        }
    }
    const int mycol = wn + q * 16 + m16;
    atomicAdd(&cs[mycol], cp[0]);   // 4-way collision (wm group)

    __syncthreads();
    if (tid < TM) atomicAdd(&rowsum[bm + tid], rs[tid]);
    else if (tid < TM + TN) atomicAdd(&colsum[bn + tid - TM], cs[tid - TM]);
}

// ---------------------------------------------------------------------------
// Kernel 3: finalize, 32 blocks, atomicAdd into out[0] (zeroed by kernel 1).
// diag dist reconstructed exactly from c2/s2/ddot (fp32).
// loss = (1/2N) * sum_i [log(rowsum_i) + log(colsum_i) + 2*e^T*dist_i]
// ---------------------------------------------------------------------------
__global__ __launch_bounds__(256) void finalize_kernel(
        const float* __restrict__ rowsum, const float* __restrict__ colsum,
        const float* __restrict__ c2, const float* __restrict__ s2,
        const float* __restrict__ ddot, const float* __restrict__ temp,
        float* __restrict__ out, int N) {
    __shared__ float red[4];
    const float escale = __expf(temp[0]);
    const int tid = threadIdx.x;
    int i = blockIdx.x * 256 + tid;
    float sum = 0.0f;
    if (i < N) {
        float d2 = c2[i] + s2[i] - 2.0f * ddot[i];
        float dist = __builtin_amdgcn_sqrtf(fmaxf(d2, 0.0f));
        sum = __logf(rowsum[i]) + __logf(colsum[i]) + 2.0f * escale * dist;
    }
    #pragma unroll
    for (int off = 32; off > 0; off >>= 1) sum += __shfl_down(sum, off, 64);
    if ((tid & 63) == 0) red[tid >> 6] = sum;
    __syncthreads();
    if (tid == 0)
        atomicAdd(out, (red[0] + red[1] + red[2] + red[3]) / (2.0f * (float)N));
}

extern "C" void kernel_launch(void* const* d_in, const int* in_sizes, int n_in,
                              void* d_out, int out_size, void* d_ws, size_t ws_size,
                              hipStream_t stream) {
    const float* C = (const float*)d_in[0];
    const float* S = (const float*)d_in[1];
    const float* T = (const float*)d_in[2];
    const int N = in_sizes[0] / DIM;   // 8192

    float* ws     = (float*)d_ws;
    float* c2     = ws;
    float* s2     = ws + N;
    float* rowsum = ws + 2 * N;
    float* colsum = ws + 3 * N;
    float* ddot   = ws + 4 * N;
    unsigned short* Cb = (unsigned short*)(ws + 5 * N + 64);  // 16B-aligned
    unsigned short* Sb = Cb + (size_t)N * DIM;

    convert_kernel<<<(N * 64) / 256, 256, 0, stream>>>(
        C, S, Cb, Sb, c2, s2, ddot, rowsum, (float*)d_out, N);

    dim3 grid(N / TN, N / TM);
    mfma_kernel<<<grid, 512, 0, stream>>>(
        Cb, Sb, c2, s2, T, rowsum, colsum, N);

    finalize_kernel<<<(N + 255) / 256, 256, 0, stream>>>(
        rowsum, colsum, c2, s2, ddot, T, (float*)d_out, N);
}

// Round 9
// 112.482 us; speedup vs baseline: 3.1536x; 1.0886x over previous
//
#include <hip/hip_runtime.h>
#include <math.h>

#define DIM 256
#define TM 256          // block tile rows (cond)
#define TN 128          // block tile cols (sol)
#define BK 64

typedef float f32x4 __attribute__((ext_vector_type(4)));
typedef long long2v __attribute__((ext_vector_type(2)));

typedef const __attribute__((address_space(1))) void* gas_ptr;
typedef __attribute__((address_space(3))) void* las_ptr;

__device__ __forceinline__ void async_cp16(const void* g, void* l) {
    __builtin_amdgcn_global_load_lds((gas_ptr)g, (las_ptr)l, 16, 0, 0);
}

// ---------------------------------------------------------------------------
// Kernel 1: fp32 -> fp8 e4m3 (HW cvt => same format the MFMA consumes) in
// FRAGMENT-MAJOR order + exact fp32 row norms + exact fp32 diag cross-dots
// + zero-init of rowsum/colsum and out[0].
// Fragment-major: within each 64-byte K-group, byte for global k
// (k = t*32 + q*8 + j) lands at q*16 + t*8 + j, so the GEMM reads ONE b128
// per (row, K-group) covering both K=32 MFMA steps of quad q.
// Lane l covers k=4l..4l+3 (same t,q; j in {0,4}) -> one 4B store.
// ---------------------------------------------------------------------------
__global__ __launch_bounds__(256) void convert_kernel(
        const float* __restrict__ C, const float* __restrict__ S,
        unsigned char* __restrict__ Cb, unsigned char* __restrict__ Sb,
        float* __restrict__ c2, float* __restrict__ s2,
        float* __restrict__ ddot, float* __restrict__ sums0,
        float* __restrict__ out, int N) {
    int gtid = blockIdx.x * 256 + threadIdx.x;
    if (gtid < 2 * N) sums0[gtid] = 0.0f;
    if (gtid == 0) out[0] = 0.0f;
    int row = gtid >> 6;
    int l = gtid & 63;
    if (row >= N) return;
    float4 v  = ((const float4*)(C + (size_t)row * DIM))[l];
    float4 sv = ((const float4*)(S + (size_t)row * DIM))[l];
    int pc = __builtin_amdgcn_cvt_pk_fp8_f32(v.x, v.y, 0, false);
    pc     = __builtin_amdgcn_cvt_pk_fp8_f32(v.z, v.w, pc, true);
    int ps = __builtin_amdgcn_cvt_pk_fp8_f32(sv.x, sv.y, 0, false);
    ps     = __builtin_amdgcn_cvt_pk_fp8_f32(sv.z, sv.w, ps, true);
    // frag-major 4B index within the row
    int idx4 = (l >> 4) * 16 + ((l & 7) >> 1) * 4 + ((l & 15) >> 3) * 2 + (l & 1);
    ((int*)(Cb + (size_t)row * DIM))[idx4] = pc;
    ((int*)(Sb + (size_t)row * DIM))[idx4] = ps;
    float nc = v.x * v.x + v.y * v.y + v.z * v.z + v.w * v.w;
    float ns = sv.x * sv.x + sv.y * sv.y + sv.z * sv.z + sv.w * sv.w;
    float cr = v.x * sv.x + v.y * sv.y + v.z * sv.z + v.w * sv.w;
    #pragma unroll
    for (int off = 32; off > 0; off >>= 1) {
        nc += __shfl_down(nc, off, 64);
        ns += __shfl_down(ns, off, 64);
        cr += __shfl_down(cr, off, 64);
    }
    if (l == 0) { c2[row] = nc; s2[row] = ns; ddot[row] = cr; }
}

// ---------------------------------------------------------------------------
// Kernel 2: fp8 MFMA GEMM, 256x128 block tile, 8 waves of 64x64 wave tiles.
// BK=64 (one frag-major K-group per iter). LDS: row = 64 B = 4 chunks of
// 16B, physical chunk = logical ^ (row&3) -> wave-uniform global_load_lds
// staging and uniform-bank b128 frag reads. One b128 = both K=32 halves
// (long2: .x = k0..31, .y = k32..63 of quad q).
// Epilogue: norms pre-scaled by K2=(e^T*log2e)^2 -> per element just
// add+fma+max+sqrt+exp2; split-exchange fold (R7) + LDS/global atomics.
// ---------------------------------------------------------------------------
__global__ __launch_bounds__(512, 4) void mfma_kernel(
        const unsigned char* __restrict__ Cb, const unsigned char* __restrict__ Sb,
        const float* __restrict__ c2, const float* __restrict__ s2,
        const float* __restrict__ temp,
        float* __restrict__ rowsum, float* __restrict__ colsum, int N) {
    __shared__ __align__(16) unsigned char Abuf[TM * BK];   // 16 KB
    __shared__ __align__(16) unsigned char Bbuf[TN * BK];   // 8 KB
    __shared__ float rs[TM], cs[TN], c2t[TM], s2t[TN];      // 3 KB

    const int tid = threadIdx.x;
    const int bm = blockIdx.y * TM;
    const int bn = blockIdx.x * TN;
    const int w  = tid >> 6;        // 0..7
    const int l  = tid & 63;
    const int wm = (w >> 1) * 64;   // 0,64,128,192
    const int wn = (w & 1) * 64;    // 0,64

    const float escale = __expf(temp[0]);
    const float Kf = escale * 1.4426950408889634f;   // e^T * log2(e)
    const float K2 = Kf * Kf;
    const float m2K2 = -2.0f * K2;

    if (tid < TM) { rs[tid] = 0.0f; c2t[tid] = K2 * c2[bm + tid]; }
    else if (tid < TM + TN) {
        int t = tid - TM; cs[t] = 0.0f; s2t[t] = K2 * s2[bn + t];
    }

    // --- staging: A slot s = i*512 + w*64 + l <-> (row = s>>2, pchunk = s&3)
    // row = i*128 + w*16 + (l>>2), pchunk = l&3; row&3 == (l>>2)&3.
    const int l4 = l >> 2;
    const int sc = (l & 3) ^ (l4 & 3);   // source logical chunk
    const unsigned char* gA = Cb + (size_t)(bm + w * 16 + l4) * DIM + sc * 16;
    const unsigned char* gB = Sb + (size_t)(bn + w * 16 + l4) * DIM + sc * 16;
    unsigned char* lA = &Abuf[w * 1024];   // + i*8192; lane offset = l*16 (HW)
    unsigned char* lB = &Bbuf[w * 1024];
    const size_t askip = (size_t)128 * DIM;   // +128 rows for A instr i=1

    // --- fragment offsets (bytes): logical chunk q at row -> phys q^(row&3)
    const int m16 = l & 15;
    const int q = l >> 4;
    int aoff[4], boff[4];
    #pragma unroll
    for (int i = 0; i < 4; ++i) {
        aoff[i] = (wm + i * 16 + m16) * BK + ((q ^ (m16 & 3)) * 16);
        boff[i] = (wn + i * 16 + m16) * BK + ((q ^ (m16 & 3)) * 16);
    }

    f32x4 acc[4][4] = {};

    #pragma unroll
    for (int kk = 0; kk < 4; ++kk) {
        async_cp16(gA, lA);
        async_cp16(gA + askip, lA + 8192);
        async_cp16(gB, lB);
        gA += BK; gB += BK;
        __syncthreads();   // staging complete (vmcnt drain)

        long2v af[4], bf[4];
        #pragma unroll
        for (int i = 0; i < 4; ++i) af[i] = *(const long2v*)&Abuf[aoff[i]];
        #pragma unroll
        for (int j = 0; j < 4; ++j) bf[j] = *(const long2v*)&Bbuf[boff[j]];
        #pragma unroll
        for (int mi = 0; mi < 4; ++mi)
            #pragma unroll
            for (int ni = 0; ni < 4; ++ni) {
                acc[mi][ni] = __builtin_amdgcn_mfma_f32_16x16x32_fp8_fp8(
                    af[mi].x, bf[ni].x, acc[mi][ni], 0, 0, 0);
                acc[mi][ni] = __builtin_amdgcn_mfma_f32_16x16x32_fp8_fp8(
                    af[mi].y, bf[ni].y, acc[mi][ni], 0, 0, 0);
            }
        __syncthreads();   // LDS consumed
    }

    // --- fused epilogue; C/D layout (m89): col = lane&15, row = q*4 + reg.
    float c2v[4][4], s2v[4];
    #pragma unroll
    for (int mi = 0; mi < 4; ++mi)
        #pragma unroll
        for (int r = 0; r < 4; ++r) c2v[mi][r] = c2t[wm + mi * 16 + q * 4 + r];
    #pragma unroll
    for (int ni = 0; ni < 4; ++ni) s2v[ni] = s2t[wn + ni * 16 + m16];

    float rp[16];   // slot s = mi*4 + r
    #pragma unroll
    for (int s = 0; s < 16; ++s) rp[s] = 0.0f;
    float cp[4] = {0.f, 0.f, 0.f, 0.f};

    #pragma unroll
    for (int mi = 0; mi < 4; ++mi) {
        #pragma unroll
        for (int ni = 0; ni < 4; ++ni) {
            #pragma unroll
            for (int r = 0; r < 4; ++r) {
                // d2'' = K2*d2; exp2(-sqrt(K2*d2)) == exp(-escale*dist)
                float d2 = fmaf(m2K2, acc[mi][ni][r], c2v[mi][r] + s2v[ni]);
                d2 = fmaxf(d2, 0.0f);
                float e = __builtin_amdgcn_exp2f(-__builtin_amdgcn_sqrtf(d2));
                rp[mi * 4 + r] += e;
                cp[ni] += e;
            }
        }
    }

    // --- split-exchange fold over the 16 lanes sharing q (R7-verified)
    #pragma unroll
    for (int b = 0; b < 4; ++b) {
        const int n = 16 >> b;
        const int bit = (m16 >> b) & 1;
        #pragma unroll
        for (int k = 0; k < 8; ++k) {
            if (k < (n >> 1)) {
                float keep = bit ? rp[2 * k + 1] : rp[2 * k];
                float send = bit ? rp[2 * k] : rp[2 * k + 1];
                float recv = __shfl_xor(send, 1 << b, 64);
                rp[k] = keep + recv;
            }
        }
    }
    const int myrow = wm + (m16 >> 2) * 16 + q * 4 + (m16 & 3);
    atomicAdd(&rs[myrow], rp[0]);   // 2-way collision (wn pair) only

    #pragma unroll
    for (int b = 0; b < 2; ++b) {
        const int n = 4 >> b;
        const int bit = (q >> b) & 1;
        #pragma unroll
        for (int k = 0; k < 2; ++k) {
            if (k < (n >> 1)) {
                float keep = bit ? cp[2 * k + 1] : cp[2 * k];
                float send = bit ? cp[2 * k] : cp[2 * k + 1];
                float recv = __shfl_xor(send, 16 << b, 64);
                cp[k] = keep + recv;
            }
        }
    }
    const int mycol = wn + q * 16 + m16;
    atomicAdd(&cs[mycol], cp[0]);   // 4-way collision (wm group)

    __syncthreads();
    if (tid < TM) atomicAdd(&rowsum[bm + tid], rs[tid]);
    else if (tid < TM + TN) atomicAdd(&colsum[bn + tid - TM], cs[tid - TM]);
}

// ---------------------------------------------------------------------------
// Kernel 3: finalize, 32 blocks, atomicAdd into out[0] (zeroed by kernel 1).
// diag dist reconstructed exactly from c2/s2/ddot (fp32).
// loss = (1/2N) * sum_i [log(rowsum_i) + log(colsum_i) + 2*e^T*dist_i]
// ---------------------------------------------------------------------------
__global__ __launch_bounds__(256) void finalize_kernel(
        const float* __restrict__ rowsum, const float* __restrict__ colsum,
        const float* __restrict__ c2, const float* __restrict__ s2,
        const float* __restrict__ ddot, const float* __restrict__ temp,
        float* __restrict__ out, int N) {
    __shared__ float red[4];
    const float escale = __expf(temp[0]);
    const int tid = threadIdx.x;
    int i = blockIdx.x * 256 + tid;
    float sum = 0.0f;
    if (i < N) {
        float d2 = c2[i] + s2[i] - 2.0f * ddot[i];
        float dist = __builtin_amdgcn_sqrtf(fmaxf(d2, 0.0f));
        sum = __logf(rowsum[i]) + __logf(colsum[i]) + 2.0f * escale * dist;
    }
    #pragma unroll
    for (int off = 32; off > 0; off >>= 1) sum += __shfl_down(sum, off, 64);
    if ((tid & 63) == 0) red[tid >> 6] = sum;
    __syncthreads();
    if (tid == 0)
        atomicAdd(out, (red[0] + red[1] + red[2] + red[3]) / (2.0f * (float)N));
}

extern "C" void kernel_launch(void* const* d_in, const int* in_sizes, int n_in,
                              void* d_out, int out_size, void* d_ws, size_t ws_size,
                              hipStream_t stream) {
    const float* C = (const float*)d_in[0];
    const float* S = (const float*)d_in[1];
    const float* T = (const float*)d_in[2];
    const int N = in_sizes[0] / DIM;   // 8192

    float* ws     = (float*)d_ws;
    float* c2     = ws;
    float* s2     = ws + N;
    float* rowsum = ws + 2 * N;
    float* colsum = ws + 3 * N;
    float* ddot   = ws + 4 * N;
    unsigned char* Cb = (unsigned char*)(ws + 5 * N + 64);  // 16B-aligned
    unsigned char* Sb = Cb + (size_t)N * DIM;

    convert_kernel<<<(N * 64) / 256, 256, 0, stream>>>(
        C, S, Cb, Sb, c2, s2, ddot, rowsum, (float*)d_out, N);

    dim3 grid(N / TN, N / TM);
    mfma_kernel<<<grid, 512, 0, stream>>>(
        Cb, Sb, c2, s2, T, rowsum, colsum, N);

    finalize_kernel<<<(N + 255) / 256, 256, 0, stream>>>(
        rowsum, colsum, c2, s2, ddot, T, (float*)d_out, N);
}